// Round 26
// baseline (158.207 us; speedup 1.0000x reference)
//
#include <hip/hip_runtime.h>
#include <cstdint>
#include <cstddef>

#define NN 50000
#define NE 1600000
#define ET (NE + NN)          // edges + self loops
#define NG 64
#define SCAN_BLOCKS ((NN + 255) / 256)   // 196
#define NB ((NN + 127) >> 7)             // 391 dst-buckets, 128 nodes each
#define CAP 6144                         // slots per bucket segment
#define EPT 16
#define EPB (256 * EPT)                  // 4096 edges per bin-block
#define BIN_BLOCKS ((ET + EPB - 1) / EPB)
#define GEMM1_BLOCKS ((NN + 63) / 64)    // 782
#define WFRAG_BLOCKS 16                  // 4096 frag-slots / 256
#define XPACK_BLOCKS 1600

typedef __attribute__((ext_vector_type(8))) short short8v;
typedef __attribute__((ext_vector_type(4))) float f32x4;

__device__ inline unsigned short f2bf(float f) {
    unsigned u = __float_as_uint(f);
    u += 0x7fffu + ((u >> 16) & 1u);     // round-to-nearest-even
    return (unsigned short)(u >> 16);
}

// ---------------- F0: bin (403) || xpack (1600) || wfrag (16) || bound (196)
__global__ __launch_bounds__(256) void k_f0(
    const int* __restrict__ esrc, const int* __restrict__ edst,
    int* __restrict__ gcnt, unsigned* __restrict__ rec,
    const float* __restrict__ x, unsigned short* __restrict__ xb,
    const float* __restrict__ W1, unsigned short* __restrict__ w1f,
    const int* __restrict__ batch, int* __restrict__ lo) {
    __shared__ int bcnt[NB];
    int bid = blockIdx.x, tid = threadIdx.x;
    if (bid < BIN_BLOCKS) {
        for (int b = tid; b < NB; b += 256) bcnt[b] = 0;
        __syncthreads();
        int e0 = bid * EPB;
        unsigned rv[EPT]; int bk[EPT]; int rk[EPT];
#pragma unroll
        for (int q = 0; q < EPT; ++q) {
            int e = e0 + q * 256 + tid;
            rk[q] = -1;
            if (e < ET) {
                int s, d;
                if (e < NE) { s = esrc[e]; d = edst[e]; } else { s = d = e - NE; }
                rv[q] = ((unsigned)s << 7) | (unsigned)(d & 127);
                bk[q] = d >> 7;
                rk[q] = atomicAdd(&bcnt[bk[q]], 1);
            }
        }
        __syncthreads();
        for (int b = tid; b < NB; b += 256)
            bcnt[b] = atomicAdd(&gcnt[b], bcnt[b]);
        __syncthreads();
#pragma unroll
        for (int q = 0; q < EPT; ++q) {
            if (rk[q] >= 0) rec[(size_t)bk[q] * CAP + bcnt[bk[q]] + rk[q]] = rv[q];
        }
    } else if (bid < BIN_BLOCKS + XPACK_BLOCKS) {
        // ---- xpack: x fp32 -> bf16, row-major, grid-stride
        int gid = (bid - BIN_BLOCKS) * 256 + tid;
        const float4* __restrict__ xf = reinterpret_cast<const float4*>(x);
        short8v* __restrict__ xo = reinterpret_cast<short8v*>(xb);
        for (size_t i = gid; i < (size_t)NN * 64; i += (size_t)XPACK_BLOCKS * 256) {
            float4 a = xf[2 * i];
            float4 b = xf[2 * i + 1];
            short8v o;
            o[0] = (short)f2bf(a.x); o[1] = (short)f2bf(a.y);
            o[2] = (short)f2bf(a.z); o[3] = (short)f2bf(a.w);
            o[4] = (short)f2bf(b.x); o[5] = (short)f2bf(b.y);
            o[6] = (short)f2bf(b.z); o[7] = (short)f2bf(b.w);
            xo[i] = o;
        }
    } else if (bid < BIN_BLOCKS + XPACK_BLOCKS + WFRAG_BLOCKS) {
        // ---- wfrag: pack W1 (512x64 fp32) into MFMA B-fragment order, bf16.
        int slot = (bid - BIN_BLOCKS - XPACK_BLOCKS) * 256 + tid;   // 0..4095
        int S = slot >> 8;
        int ct = (slot >> 6) & 3;
        int l = slot & 63;
        int kb = S * 32 + ((l >> 4) << 3);
        int c = ct * 16 + (l & 15);
        unsigned short* dst = w1f + (size_t)slot * 8;
#pragma unroll
        for (int j = 0; j < 8; ++j)
            dst[j] = f2bf(W1[(kb + j) * 64 + c]);
    } else {
        int n = (bid - BIN_BLOCKS - XPACK_BLOCKS - WFRAG_BLOCKS) * 256 + tid;
        if (n >= NN) return;
        int b = batch[n];
        if (n == 0) {
            for (int g = 0; g <= b; ++g) lo[g] = 0;
        } else {
            int pb = batch[n - 1];
            for (int g = pb + 1; g <= b; ++g) lo[g] = n;
        }
        if (n == NN - 1) {
            for (int g = b + 1; g <= NG; ++g) lo[g] = NN;
        }
    }
}

// ---------------- F1: unbin2 (391 blocks) || gemm1-MFMA direct bf16 loads (782).
__global__ __launch_bounds__(256, 6) void k_f1(
    const int* __restrict__ gcnt, const unsigned* __restrict__ rec,
    int* __restrict__ obeg, int* __restrict__ oend, int* __restrict__ csr,
    const unsigned short* __restrict__ xb, const unsigned short* __restrict__ w1f,
    const float* __restrict__ aS, const float* __restrict__ aD,
    unsigned short* __restrict__ h1b, float* __restrict__ as1, float* __restrict__ ad1) {
    __shared__ int sm[256];           // 1 KB, unbin2 only
    int bid = blockIdx.x, t = threadIdx.x;

    if (bid < NB) {
        // ======== unbin2 ========
        int* cnt  = sm;
        int* lcur = sm + 128;
        int b = bid, tid = t;
        if (tid < 128) cnt[tid] = 0;
        __syncthreads();
        size_t base = (size_t)b * CAP;
        int nrec = gcnt[b];
        for (int i = tid; i < nrec; i += 256)
            atomicAdd(&cnt[rec[base + i] & 127], 1);
        __syncthreads();
        int v = 0, incl = 0;
        if (tid < 128) {
            int lane = tid & 63;
            v = cnt[tid];
            incl = v;
#pragma unroll
            for (int ofs = 1; ofs < 64; ofs <<= 1) {
                int o = __shfl_up(incl, ofs);
                if (lane >= ofs) incl += o;
            }
            cnt[tid] = incl;
        }
        __syncthreads();
        if (tid < 128) {
            int ex = incl - v + ((tid >= 64) ? cnt[63] : 0);
            int n = (b << 7) + tid;
            int pos = (int)base + ex;
            if (n < NN) { obeg[n] = pos; oend[n] = pos + v; }
            lcur[tid] = pos;
        }
        __syncthreads();
        for (int i = tid; i < nrec; i += 256) {
            unsigned r = rec[base + i];
            int pos = atomicAdd(&lcur[r & 127], 1);
            csr[pos] = (int)(r >> 7);
        }
    } else {
        // ======== gemm1-MFMA: A direct 16B bf16 load, B frags from L2-resident w1f ========
        int w = t >> 6, l = t & 63;
        int n0 = (bid - NB) * 64;
        int rrow = n0 + w * 16 + (l & 15);                // A-load row for this lane
        int rc = (rrow < NN) ? rrow : (NN - 1);
        const short8v* __restrict__ xbr = reinterpret_cast<const short8v*>(xb) + (size_t)rc * 64;
        const short8v* __restrict__ wv8 = reinterpret_cast<const short8v*>(w1f);

        f32x4 acc0 = {0.f, 0.f, 0.f, 0.f};
        f32x4 acc1 = {0.f, 0.f, 0.f, 0.f};
        f32x4 acc2 = {0.f, 0.f, 0.f, 0.f};
        f32x4 acc3 = {0.f, 0.f, 0.f, 0.f};

        int la = l >> 4;   // A-frag short8v index within 32-k step
#pragma unroll 4
        for (int s = 0; s < 16; ++s) {
            short8v af = xbr[s * 4 + la];
            const short8v* bp = wv8 + (size_t)(s * 4) * 64 + l;
            short8v bf0 = bp[0];
            short8v bf1 = bp[64];
            short8v bf2 = bp[128];
            short8v bf3 = bp[192];
            acc0 = __builtin_amdgcn_mfma_f32_16x16x32_bf16(af, bf0, acc0, 0, 0, 0);
            acc1 = __builtin_amdgcn_mfma_f32_16x16x32_bf16(af, bf1, acc1, 0, 0, 0);
            acc2 = __builtin_amdgcn_mfma_f32_16x16x32_bf16(af, bf2, acc2, 0, 0, 0);
            acc3 = __builtin_amdgcn_mfma_f32_16x16x32_bf16(af, bf3, acc3, 0, 0, 0);
        }

        // epilogue: C/D layout col=lane&15, row=(lane>>4)*4+reg (m89-verified)
        int hi = (l & 15) >> 3;   // head parity
        int cc = l & 7;           // channel within head
#pragma unroll
        for (int reg = 0; reg < 4; ++reg) {
            int row16 = ((l >> 4) << 2) + reg;
            int r = n0 + w * 16 + row16;
            float v0 = acc0[reg], v1 = acc1[reg], v2 = acc2[reg], v3 = acc3[reg];
            if (r < NN) {
                unsigned short* hp = h1b + (size_t)r * 64 + (l & 15);
                hp[0]  = f2bf(v0);
                hp[16] = f2bf(v1);
                hp[32] = f2bf(v2);
                hp[48] = f2bf(v3);
            }
            float ps[4], pd[4];
            float vv[4] = {v0, v1, v2, v3};
#pragma unroll
            for (int ct = 0; ct < 4; ++ct) {
                int h = ct * 2 + hi;
                ps[ct] = vv[ct] * aS[h * 8 + cc];
                pd[ct] = vv[ct] * aD[h * 8 + cc];
            }
#pragma unroll
            for (int ofs = 1; ofs <= 4; ofs <<= 1) {
#pragma unroll
                for (int ct = 0; ct < 4; ++ct) {
                    ps[ct] += __shfl_xor(ps[ct], ofs);
                    pd[ct] += __shfl_xor(pd[ct], ofs);
                }
            }
            if (cc == 0 && r < NN) {
#pragma unroll
                for (int ct = 0; ct < 4; ++ct) {
                    int h = ct * 2 + hi;
                    as1[r * 8 + h] = ps[ct];
                    ad1[r * 8 + h] = pd[ct];
                }
            }
        }
    }
}

// ---------------- K4: fused layer-1 aggregation + layer-2 GEMM. h1 gathered as bf16.
__global__ __launch_bounds__(256) void k_agg1g(
    const int* __restrict__ obeg, const int* __restrict__ oend, const int* __restrict__ csr,
    const unsigned short* __restrict__ h1b, const float* __restrict__ as1, const float* __restrict__ ad1,
    const float* __restrict__ bias1, const float* __restrict__ W2,
    const float* __restrict__ aS2, const float* __restrict__ aD2,
    unsigned short* __restrict__ h2b, float* __restrict__ as2, float* __restrict__ ad2) {
    __shared__ float w2l[64 * 32];     // 8 KB
    __shared__ float h1ol[4][64];      // per-wave h1o row
    int tid = threadIdx.x;
    for (int i = tid; i < 2048; i += 256) w2l[i] = W2[i];
    __syncthreads();

    int l = tid & 63;
    int wv = tid >> 6;
    int dst = blockIdx.x * 4 + wv;
    if (dst >= NN) return;
    int g = l >> 4;            // edge slot 0..3
    int q = l & 15;            // 4-channel group
    int h = q >> 1;            // head
    int beg = obeg[dst], end = oend[dst];
    int lastj = end - 1;
    float adh = ad1[dst * 8 + h];
    const uint2* __restrict__ h1u = reinterpret_cast<const uint2*>(h1b);

    float4 acc = make_float4(0.f, 0.f, 0.f, 0.f);
    float dsum = 0.f;

    int sA[4], sB[4];
#pragma unroll
    for (int p = 0; p < 4; ++p) sA[p] = csr[min(beg + p * 4 + g, lastj)];
    for (int j = beg; j < end; j += 16) {
#pragma unroll
        for (int p = 0; p < 4; ++p) sB[p] = csr[min(j + 16 + p * 4 + g, lastj)];
        float av[4]; uint2 vv[4];
#pragma unroll
        for (int p = 0; p < 4; ++p) {
            av[p] = as1[sA[p] * 8 + h];
            vv[p] = h1u[(size_t)sA[p] * 16 + q];
        }
#pragma unroll
        for (int p = 0; p < 4; ++p) {
            float e = av[p] + adh; e = (e > 0.f) ? e : 0.2f * e;
            float w = __expf(e);
            w = (j + p * 4 + g < end) ? w : 0.f;
            float x0 = __uint_as_float(vv[p].x << 16);
            float x1 = __uint_as_float(vv[p].x & 0xffff0000u);
            float x2 = __uint_as_float(vv[p].y << 16);
            float x3 = __uint_as_float(vv[p].y & 0xffff0000u);
            acc.x += w * x0; acc.y += w * x1;
            acc.z += w * x2; acc.w += w * x3;
            dsum += w;
        }
#pragma unroll
        for (int p = 0; p < 4; ++p) sA[p] = sB[p];
    }

#pragma unroll
    for (int ofs = 16; ofs <= 32; ofs <<= 1) {
        acc.x += __shfl_xor(acc.x, ofs);
        acc.y += __shfl_xor(acc.y, ofs);
        acc.z += __shfl_xor(acc.z, ofs);
        acc.w += __shfl_xor(acc.w, ofs);
        dsum  += __shfl_xor(dsum, ofs);
    }

    if (g == 0) {
        float inv = 1.f / (dsum + 1e-16f);
        const float4 bq = reinterpret_cast<const float4*>(bias1)[q];
        float4 r;
        r.x = acc.x * inv + bq.x;
        r.y = acc.y * inv + bq.y;
        r.z = acc.z * inv + bq.z;
        r.w = acc.w * inv + bq.w;
        r.x = (r.x > 0.f) ? r.x : (__expf(r.x) - 1.f);
        r.y = (r.y > 0.f) ? r.y : (__expf(r.y) - 1.f);
        r.z = (r.z > 0.f) ? r.z : (__expf(r.z) - 1.f);
        r.w = (r.w > 0.f) ? r.w : (__expf(r.w) - 1.f);
        h1ol[wv][q * 4 + 0] = r.x;
        h1ol[wv][q * 4 + 1] = r.y;
        h1ol[wv][q * 4 + 2] = r.z;
        h1ol[wv][q * 4 + 3] = r.w;
    }

    // fused gemm2; h2 stored bf16
    int c = l & 31, half = l >> 5;
    const float* hrow = h1ol[wv];
    float acc2 = 0.f;
#pragma unroll 8
    for (int kk = 0; kk < 32; ++kk) {
        int k = half * 32 + kk;
        acc2 += hrow[k] * w2l[k * 32 + c];
    }
    acc2 += __shfl_xor(acc2, 32);
    if (l < 32) h2b[(size_t)dst * 32 + c] = f2bf(acc2);
    float ps = acc2 * aS2[c], pd = acc2 * aD2[c];
#pragma unroll
    for (int ofs = 1; ofs <= 16; ofs <<= 1) {
        ps += __shfl_xor(ps, ofs);
        pd += __shfl_xor(pd, ofs);
    }
    if (l == 0) { as2[dst] = ps; ad2[dst] = pd; }
}

// ---------------- K7: layer-2 aggregation; h2 gathered as bf16. o2 fp32.
__global__ __launch_bounds__(256) void k_agg2(
    const int* __restrict__ obeg, const int* __restrict__ oend, const int* __restrict__ csr,
    const unsigned short* __restrict__ h2b, const float* __restrict__ as2, const float* __restrict__ ad2,
    const float* __restrict__ bias2, float* __restrict__ o2) {
    int l = threadIdx.x & 63;
    int dst = blockIdx.x * 4 + (threadIdx.x >> 6);
    if (dst >= NN) return;
    int g = l >> 3;            // edge slot 0..7
    int q = l & 7;             // 4-channel group
    int beg = obeg[dst], end = oend[dst];
    int lastj = end - 1;
    float adh = ad2[dst];
    const uint2* __restrict__ h2u = reinterpret_cast<const uint2*>(h2b);

    float4 acc = make_float4(0.f, 0.f, 0.f, 0.f);
    float dsum = 0.f;

    int sA[4], sB[4];
#pragma unroll
    for (int p = 0; p < 4; ++p) sA[p] = csr[min(beg + p * 8 + g, lastj)];
    for (int j = beg; j < end; j += 32) {
#pragma unroll
        for (int p = 0; p < 4; ++p) sB[p] = csr[min(j + 32 + p * 8 + g, lastj)];
        float av[4]; uint2 vv[4];
#pragma unroll
        for (int p = 0; p < 4; ++p) {
            av[p] = as2[sA[p]];
            vv[p] = h2u[(size_t)sA[p] * 8 + q];
        }
#pragma unroll
        for (int p = 0; p < 4; ++p) {
            float e = av[p] + adh; e = (e > 0.f) ? e : 0.2f * e;
            float w = __expf(e);
            w = (j + p * 8 + g < end) ? w : 0.f;
            float x0 = __uint_as_float(vv[p].x << 16);
            float x1 = __uint_as_float(vv[p].x & 0xffff0000u);
            float x2 = __uint_as_float(vv[p].y << 16);
            float x3 = __uint_as_float(vv[p].y & 0xffff0000u);
            acc.x += w * x0; acc.y += w * x1;
            acc.z += w * x2; acc.w += w * x3;
            dsum += w;
        }
#pragma unroll
        for (int p = 0; p < 4; ++p) sA[p] = sB[p];
    }

#pragma unroll
    for (int ofs = 8; ofs <= 32; ofs <<= 1) {
        acc.x += __shfl_xor(acc.x, ofs);
        acc.y += __shfl_xor(acc.y, ofs);
        acc.z += __shfl_xor(acc.z, ofs);
        acc.w += __shfl_xor(acc.w, ofs);
        dsum  += __shfl_xor(dsum, ofs);
    }

    if (g == 0) {
        float inv = 1.f / (dsum + 1e-16f);
        const float4 bq = reinterpret_cast<const float4*>(bias2)[q];
        float4 r;
        r.x = acc.x * inv + bq.x;
        r.y = acc.y * inv + bq.y;
        r.z = acc.z * inv + bq.z;
        r.w = acc.w * inv + bq.w;
        reinterpret_cast<float4*>(o2)[dst * 8 + q] = r;
    }
}

// ---------------- K9: pooled sums.
__global__ __launch_bounds__(256) void k_pool(const float* __restrict__ o2, const int* __restrict__ lo,
                                              float* __restrict__ pooled) {
    __shared__ float red[256];
    int g = blockIdx.x & 63, q = blockIdx.x >> 6;
    int beg = lo[g], end = lo[g + 1];
    int c = threadIdx.x & 31, row = threadIdx.x >> 5;
    float s = 0.f;
    for (int n = beg + q * 8 + row; n < end; n += 32) s += o2[n * 32 + c];
    red[threadIdx.x] = s;
    __syncthreads();
    for (int rr = 4; rr >= 1; rr >>= 1) {
        if (row < rr) red[threadIdx.x] += red[(row + rr) * 32 + c];
        __syncthreads();
    }
    if (row == 0) atomicAdd(&pooled[g * 32 + c], red[c]);
}

// ---------------- K10: mean + final linear -> out[64][2]
__global__ void k_fin(const float* __restrict__ pooled, const int* __restrict__ lo,
                      const float* __restrict__ lw, const float* __restrict__ lb,
                      float* __restrict__ out) {
    int t = threadIdx.x;
    if (t >= 128) return;
    int g = t >> 1, o = t & 1;
    int cnt = lo[g + 1] - lo[g];
    float inv = 1.f / fmaxf((float)cnt, 1.f);
    float s = 0.f;
#pragma unroll
    for (int c = 0; c < 32; ++c) s += pooled[g * 32 + c] * lw[c * 2 + o];
    out[g * 2 + o] = s * inv + lb[o];
}

// ----------------------------------------------------------------------------
extern "C" void kernel_launch(void* const* d_in, const int* in_sizes, int n_in,
                              void* d_out, int out_size, void* d_ws, size_t ws_size,
                              hipStream_t stream) {
    const float* x   = (const float*)d_in[0];
    const int*   ei  = (const int*)d_in[1];     // [2][NE]
    const int*   bat = (const int*)d_in[2];
    const float* W1  = (const float*)d_in[3];
    const float* aS1 = (const float*)d_in[4];
    const float* aD1 = (const float*)d_in[5];
    const float* b1  = (const float*)d_in[6];
    const float* W2  = (const float*)d_in[7];
    const float* aS2 = (const float*)d_in[8];
    const float* aD2 = (const float*)d_in[9];
    const float* b2  = (const float*)d_in[10];
    const float* lw  = (const float*)d_in[11];
    const float* lb  = (const float*)d_in[12];
    float* out = (float*)d_out;

    const int* esrc = ei;
    const int* edst = ei + NE;

    char* ws = (char*)d_ws;
    size_t off = 0;
    auto alloc = [&](size_t bytes) -> void* {
        off = (off + 255) & ~(size_t)255;
        void* p = ws + off;
        off += bytes;
        return p;
    };

    unsigned short* xb  = (unsigned short*)alloc((size_t)NN * 512 * 2);
    unsigned short* h1b = (unsigned short*)alloc((size_t)NN * 64 * 2);
    unsigned short* h2b = (unsigned short*)alloc((size_t)NN * 32 * 2);
    float* o2   = (float*)alloc((size_t)NN * 32 * 4);
    float* as1  = (float*)alloc((size_t)NN * 8 * 4);
    float* ad1  = (float*)alloc((size_t)NN * 8 * 4);
    float* as2  = (float*)alloc((size_t)NN * 4);
    float* ad2  = (float*)alloc((size_t)NN * 4);
    int*   obeg = (int*)alloc((size_t)NN * 4);
    int*   oend = (int*)alloc((size_t)NN * 4);
    int*   csr  = (int*)alloc((size_t)NB * CAP * 4);
    unsigned* rec = (unsigned*)alloc((size_t)NB * CAP * 4);
    int*   gcnt = (int*)alloc((size_t)NB * 4);
    unsigned short* w1f = (unsigned short*)alloc((size_t)512 * 64 * 2);
    float* pooled = (float*)alloc((size_t)NG * 32 * 4);
    int*   lo   = (int*)alloc((size_t)(NG + 1) * 4);
    if (off > ws_size) return;   // workspace too small: leave d_out poisoned (visible failure)

    hipMemsetAsync(gcnt, 0, (size_t)NB * 4, stream);
    hipMemsetAsync(pooled, 0, (size_t)NG * 32 * 4, stream);

    k_f0<<<BIN_BLOCKS + XPACK_BLOCKS + WFRAG_BLOCKS + SCAN_BLOCKS, 256, 0, stream>>>(
        esrc, edst, gcnt, rec, x, xb, W1, w1f, bat, lo);
    k_f1<<<NB + GEMM1_BLOCKS, 256, 0, stream>>>(
        gcnt, rec, obeg, oend, csr, xb, w1f, aS1, aD1, h1b, as1, ad1);

    k_agg1g<<<(NN + 3) / 4, 256, 0, stream>>>(obeg, oend, csr, h1b, as1, ad1, b1,
                                              W2, aS2, aD2, h2b, as2, ad2);
    k_agg2<<<(NN + 3) / 4, 256, 0, stream>>>(obeg, oend, csr, h2b, as2, ad2, b2, o2);

    k_pool<<<NG * 4, 256, 0, stream>>>(o2, lo, pooled);
    k_fin<<<1, 128, 0, stream>>>(pooled, lo, lw, lb, out);
}

// Round 27
// 148.825 us; speedup vs baseline: 1.0630x; 1.0630x over previous
//
#include <hip/hip_runtime.h>
#include <cstdint>
#include <cstddef>

#define NN 50000
#define NE 1600000
#define ET (NE + NN)          // edges + self loops
#define NG 64
#define SCAN_BLOCKS ((NN + 255) / 256)   // 196
#define NB ((NN + 127) >> 7)             // 391 dst-buckets, 128 nodes each
#define CAP 6144                         // slots per bucket segment
#define EPT 16
#define EPB (256 * EPT)                  // 4096 edges per bin-block
#define BIN_BLOCKS ((ET + EPB - 1) / EPB)
#define G1H 391                          // gemm1 half-grid (782 total)

typedef __attribute__((ext_vector_type(8))) short short8v;
typedef __attribute__((ext_vector_type(4))) float f32x4;

__device__ inline unsigned short f2bf(float f) {
    unsigned u = __float_as_uint(f);
    u += 0x7fffu + ((u >> 16) & 1u);     // round-to-nearest-even
    return (unsigned short)(u >> 16);
}

// ---- gemm1 block body: 64 rows at n0, MFMA bf16, direct fp32 A loads.
__device__ __forceinline__ void gemm1_block(
    int n0, int t,
    const float* __restrict__ x, const unsigned short* __restrict__ w1f,
    const float* __restrict__ aS, const float* __restrict__ aD,
    unsigned short* __restrict__ h1b, float* __restrict__ as1, float* __restrict__ ad1) {
    int w = t >> 6, l = t & 63;
    int rrow = n0 + w * 16 + (l & 15);
    int rc = (rrow < NN) ? rrow : (NN - 1);
    const float* __restrict__ xr = x + (size_t)rc * 512;
    const short8v* __restrict__ wv8 = reinterpret_cast<const short8v*>(w1f);

    f32x4 acc0 = {0.f, 0.f, 0.f, 0.f};
    f32x4 acc1 = {0.f, 0.f, 0.f, 0.f};
    f32x4 acc2 = {0.f, 0.f, 0.f, 0.f};
    f32x4 acc3 = {0.f, 0.f, 0.f, 0.f};

    int lk = (l >> 4) << 3;   // k-offset of this lane's A frag within a 32-k step
#pragma unroll 4
    for (int s = 0; s < 16; ++s) {
        const float4* xp = reinterpret_cast<const float4*>(xr + s * 32 + lk);
        float4 a0 = xp[0];
        float4 a1 = xp[1];
        short8v af;
        af[0] = (short)f2bf(a0.x); af[1] = (short)f2bf(a0.y);
        af[2] = (short)f2bf(a0.z); af[3] = (short)f2bf(a0.w);
        af[4] = (short)f2bf(a1.x); af[5] = (short)f2bf(a1.y);
        af[6] = (short)f2bf(a1.z); af[7] = (short)f2bf(a1.w);
        const short8v* bp = wv8 + (size_t)(s * 4) * 64 + l;
        short8v bf0 = bp[0];
        short8v bf1 = bp[64];
        short8v bf2 = bp[128];
        short8v bf3 = bp[192];
        acc0 = __builtin_amdgcn_mfma_f32_16x16x32_bf16(af, bf0, acc0, 0, 0, 0);
        acc1 = __builtin_amdgcn_mfma_f32_16x16x32_bf16(af, bf1, acc1, 0, 0, 0);
        acc2 = __builtin_amdgcn_mfma_f32_16x16x32_bf16(af, bf2, acc2, 0, 0, 0);
        acc3 = __builtin_amdgcn_mfma_f32_16x16x32_bf16(af, bf3, acc3, 0, 0, 0);
    }

    // epilogue: C/D layout col=lane&15, row=(lane>>4)*4+reg (m89-verified)
    int hi = (l & 15) >> 3;
    int cc = l & 7;
#pragma unroll
    for (int reg = 0; reg < 4; ++reg) {
        int row16 = ((l >> 4) << 2) + reg;
        int r = n0 + w * 16 + row16;
        float v0 = acc0[reg], v1 = acc1[reg], v2 = acc2[reg], v3 = acc3[reg];
        if (r < NN) {
            unsigned short* hp = h1b + (size_t)r * 64 + (l & 15);
            hp[0]  = f2bf(v0);
            hp[16] = f2bf(v1);
            hp[32] = f2bf(v2);
            hp[48] = f2bf(v3);
        }
        float ps[4], pd[4];
        float vv[4] = {v0, v1, v2, v3};
#pragma unroll
        for (int ct = 0; ct < 4; ++ct) {
            int h = ct * 2 + hi;
            ps[ct] = vv[ct] * aS[h * 8 + cc];
            pd[ct] = vv[ct] * aD[h * 8 + cc];
        }
#pragma unroll
        for (int ofs = 1; ofs <= 4; ofs <<= 1) {
#pragma unroll
            for (int ct = 0; ct < 4; ++ct) {
                ps[ct] += __shfl_xor(ps[ct], ofs);
                pd[ct] += __shfl_xor(pd[ct], ofs);
            }
        }
        if (cc == 0 && r < NN) {
#pragma unroll
            for (int ct = 0; ct < 4; ++ct) {
                int h = ct * 2 + hi;
                as1[r * 8 + h] = ps[ct];
                ad1[r * 8 + h] = pd[ct];
            }
        }
    }
}

// ---------------- WF: pack W1 into MFMA B-fragment order, bf16 (16 blocks).
__global__ __launch_bounds__(256) void k_wf(const float* __restrict__ W1,
                                            unsigned short* __restrict__ w1f) {
    int slot = blockIdx.x * 256 + threadIdx.x;   // 0..4095
    int S = slot >> 8;
    int ct = (slot >> 6) & 3;
    int l = slot & 63;
    int kb = S * 32 + ((l >> 4) << 3);
    int c = ct * 16 + (l & 15);
    unsigned short* dst = w1f + (size_t)slot * 8;
#pragma unroll
    for (int j = 0; j < 8; ++j)
        dst[j] = f2bf(W1[(kb + j) * 64 + c]);
}

// ---------------- FA: gemm1-half1 (391) || bin (403) || bound (196)
__global__ __launch_bounds__(256) void k_fa(
    const float* __restrict__ x, const unsigned short* __restrict__ w1f,
    const float* __restrict__ aS, const float* __restrict__ aD,
    unsigned short* __restrict__ h1b, float* __restrict__ as1, float* __restrict__ ad1,
    const int* __restrict__ esrc, const int* __restrict__ edst,
    int* __restrict__ gcnt, unsigned* __restrict__ rec,
    const int* __restrict__ batch, int* __restrict__ lo) {
    __shared__ int bcnt[NB];
    int bid = blockIdx.x, tid = threadIdx.x;
    if (bid < G1H) {
        gemm1_block(bid * 64, tid, x, w1f, aS, aD, h1b, as1, ad1);
    } else if (bid < G1H + BIN_BLOCKS) {
        // ---- bin: block-aggregated bucket scatter into fixed segments
        for (int b = tid; b < NB; b += 256) bcnt[b] = 0;
        __syncthreads();
        int e0 = (bid - G1H) * EPB;
        unsigned rv[EPT]; int bk[EPT]; int rk[EPT];
#pragma unroll
        for (int q = 0; q < EPT; ++q) {
            int e = e0 + q * 256 + tid;
            rk[q] = -1;
            if (e < ET) {
                int s, d;
                if (e < NE) { s = esrc[e]; d = edst[e]; } else { s = d = e - NE; }
                rv[q] = ((unsigned)s << 7) | (unsigned)(d & 127);
                bk[q] = d >> 7;
                rk[q] = atomicAdd(&bcnt[bk[q]], 1);
            }
        }
        __syncthreads();
        for (int b = tid; b < NB; b += 256)
            bcnt[b] = atomicAdd(&gcnt[b], bcnt[b]);
        __syncthreads();
#pragma unroll
        for (int q = 0; q < EPT; ++q) {
            if (rk[q] >= 0) rec[(size_t)bk[q] * CAP + bcnt[bk[q]] + rk[q]] = rv[q];
        }
    } else {
        // ---- bound
        int n = (bid - G1H - BIN_BLOCKS) * 256 + tid;
        if (n >= NN) return;
        int b = batch[n];
        if (n == 0) {
            for (int g = 0; g <= b; ++g) lo[g] = 0;
        } else {
            int pb = batch[n - 1];
            for (int g = pb + 1; g <= b; ++g) lo[g] = n;
        }
        if (n == NN - 1) {
            for (int g = b + 1; g <= NG; ++g) lo[g] = NN;
        }
    }
}

// ---------------- FB: gemm1-half2 (391) || unbin2 (391)
__global__ __launch_bounds__(256) void k_fb(
    const float* __restrict__ x, const unsigned short* __restrict__ w1f,
    const float* __restrict__ aS, const float* __restrict__ aD,
    unsigned short* __restrict__ h1b, float* __restrict__ as1, float* __restrict__ ad1,
    const int* __restrict__ gcnt, const unsigned* __restrict__ rec,
    int* __restrict__ obeg, int* __restrict__ oend, int* __restrict__ csr) {
    __shared__ int sm[256];
    int bid = blockIdx.x, tid = threadIdx.x;
    if (bid < G1H) {
        gemm1_block((G1H + bid) * 64, tid, x, w1f, aS, aD, h1b, as1, ad1);
    } else {
        // ======== unbin2 ========
        int* cnt  = sm;
        int* lcur = sm + 128;
        int b = bid - G1H;
        if (tid < 128) cnt[tid] = 0;
        __syncthreads();
        size_t base = (size_t)b * CAP;
        int nrec = gcnt[b];
        for (int i = tid; i < nrec; i += 256)
            atomicAdd(&cnt[rec[base + i] & 127], 1);
        __syncthreads();
        int v = 0, incl = 0;
        if (tid < 128) {
            int lane = tid & 63;
            v = cnt[tid];
            incl = v;
#pragma unroll
            for (int ofs = 1; ofs < 64; ofs <<= 1) {
                int o = __shfl_up(incl, ofs);
                if (lane >= ofs) incl += o;
            }
            cnt[tid] = incl;
        }
        __syncthreads();
        if (tid < 128) {
            int ex = incl - v + ((tid >= 64) ? cnt[63] : 0);
            int n = (b << 7) + tid;
            int pos = (int)base + ex;
            if (n < NN) { obeg[n] = pos; oend[n] = pos + v; }
            lcur[tid] = pos;
        }
        __syncthreads();
        for (int i = tid; i < nrec; i += 256) {
            unsigned r = rec[base + i];
            int pos = atomicAdd(&lcur[r & 127], 1);
            csr[pos] = (int)(r >> 7);
        }
    }
}

// ---------------- K4: fused layer-1 aggregation + layer-2 GEMM. h1 gathered as bf16.
__global__ __launch_bounds__(256) void k_agg1g(
    const int* __restrict__ obeg, const int* __restrict__ oend, const int* __restrict__ csr,
    const unsigned short* __restrict__ h1b, const float* __restrict__ as1, const float* __restrict__ ad1,
    const float* __restrict__ bias1, const float* __restrict__ W2,
    const float* __restrict__ aS2, const float* __restrict__ aD2,
    unsigned short* __restrict__ h2b, float* __restrict__ as2, float* __restrict__ ad2) {
    __shared__ float w2l[64 * 32];     // 8 KB
    __shared__ float h1ol[4][64];      // per-wave h1o row
    int tid = threadIdx.x;
    for (int i = tid; i < 2048; i += 256) w2l[i] = W2[i];
    __syncthreads();

    int l = tid & 63;
    int wv = tid >> 6;
    int dst = blockIdx.x * 4 + wv;
    if (dst >= NN) return;
    int g = l >> 4;            // edge slot 0..3
    int q = l & 15;            // 4-channel group
    int h = q >> 1;            // head
    int beg = obeg[dst], end = oend[dst];
    int lastj = end - 1;
    float adh = ad1[dst * 8 + h];
    const uint2* __restrict__ h1u = reinterpret_cast<const uint2*>(h1b);

    float4 acc = make_float4(0.f, 0.f, 0.f, 0.f);
    float dsum = 0.f;

    int sA[4], sB[4];
#pragma unroll
    for (int p = 0; p < 4; ++p) sA[p] = csr[min(beg + p * 4 + g, lastj)];
    for (int j = beg; j < end; j += 16) {
#pragma unroll
        for (int p = 0; p < 4; ++p) sB[p] = csr[min(j + 16 + p * 4 + g, lastj)];
        float av[4]; uint2 vv[4];
#pragma unroll
        for (int p = 0; p < 4; ++p) {
            av[p] = as1[sA[p] * 8 + h];
            vv[p] = h1u[(size_t)sA[p] * 16 + q];
        }
#pragma unroll
        for (int p = 0; p < 4; ++p) {
            float e = av[p] + adh; e = (e > 0.f) ? e : 0.2f * e;
            float w = __expf(e);
            w = (j + p * 4 + g < end) ? w : 0.f;
            float x0 = __uint_as_float(vv[p].x << 16);
            float x1 = __uint_as_float(vv[p].x & 0xffff0000u);
            float x2 = __uint_as_float(vv[p].y << 16);
            float x3 = __uint_as_float(vv[p].y & 0xffff0000u);
            acc.x += w * x0; acc.y += w * x1;
            acc.z += w * x2; acc.w += w * x3;
            dsum += w;
        }
#pragma unroll
        for (int p = 0; p < 4; ++p) sA[p] = sB[p];
    }

#pragma unroll
    for (int ofs = 16; ofs <= 32; ofs <<= 1) {
        acc.x += __shfl_xor(acc.x, ofs);
        acc.y += __shfl_xor(acc.y, ofs);
        acc.z += __shfl_xor(acc.z, ofs);
        acc.w += __shfl_xor(acc.w, ofs);
        dsum  += __shfl_xor(dsum, ofs);
    }

    if (g == 0) {
        float inv = 1.f / (dsum + 1e-16f);
        const float4 bq = reinterpret_cast<const float4*>(bias1)[q];
        float4 r;
        r.x = acc.x * inv + bq.x;
        r.y = acc.y * inv + bq.y;
        r.z = acc.z * inv + bq.z;
        r.w = acc.w * inv + bq.w;
        r.x = (r.x > 0.f) ? r.x : (__expf(r.x) - 1.f);
        r.y = (r.y > 0.f) ? r.y : (__expf(r.y) - 1.f);
        r.z = (r.z > 0.f) ? r.z : (__expf(r.z) - 1.f);
        r.w = (r.w > 0.f) ? r.w : (__expf(r.w) - 1.f);
        h1ol[wv][q * 4 + 0] = r.x;
        h1ol[wv][q * 4 + 1] = r.y;
        h1ol[wv][q * 4 + 2] = r.z;
        h1ol[wv][q * 4 + 3] = r.w;
    }

    // fused gemm2; h2 stored bf16
    int c = l & 31, half = l >> 5;
    const float* hrow = h1ol[wv];
    float acc2 = 0.f;
#pragma unroll 8
    for (int kk = 0; kk < 32; ++kk) {
        int k = half * 32 + kk;
        acc2 += hrow[k] * w2l[k * 32 + c];
    }
    acc2 += __shfl_xor(acc2, 32);
    if (l < 32) h2b[(size_t)dst * 32 + c] = f2bf(acc2);
    float ps = acc2 * aS2[c], pd = acc2 * aD2[c];
#pragma unroll
    for (int ofs = 1; ofs <= 16; ofs <<= 1) {
        ps += __shfl_xor(ps, ofs);
        pd += __shfl_xor(pd, ofs);
    }
    if (l == 0) { as2[dst] = ps; ad2[dst] = pd; }
}

// ---------------- K7: layer-2 aggregation; h2 gathered as bf16. o2 fp32.
__global__ __launch_bounds__(256) void k_agg2(
    const int* __restrict__ obeg, const int* __restrict__ oend, const int* __restrict__ csr,
    const unsigned short* __restrict__ h2b, const float* __restrict__ as2, const float* __restrict__ ad2,
    const float* __restrict__ bias2, float* __restrict__ o2) {
    int l = threadIdx.x & 63;
    int dst = blockIdx.x * 4 + (threadIdx.x >> 6);
    if (dst >= NN) return;
    int g = l >> 3;            // edge slot 0..7
    int q = l & 7;             // 4-channel group
    int beg = obeg[dst], end = oend[dst];
    int lastj = end - 1;
    float adh = ad2[dst];
    const uint2* __restrict__ h2u = reinterpret_cast<const uint2*>(h2b);

    float4 acc = make_float4(0.f, 0.f, 0.f, 0.f);
    float dsum = 0.f;

    int sA[4], sB[4];
#pragma unroll
    for (int p = 0; p < 4; ++p) sA[p] = csr[min(beg + p * 8 + g, lastj)];
    for (int j = beg; j < end; j += 32) {
#pragma unroll
        for (int p = 0; p < 4; ++p) sB[p] = csr[min(j + 32 + p * 8 + g, lastj)];
        float av[4]; uint2 vv[4];
#pragma unroll
        for (int p = 0; p < 4; ++p) {
            av[p] = as2[sA[p]];
            vv[p] = h2u[(size_t)sA[p] * 8 + q];
        }
#pragma unroll
        for (int p = 0; p < 4; ++p) {
            float e = av[p] + adh; e = (e > 0.f) ? e : 0.2f * e;
            float w = __expf(e);
            w = (j + p * 8 + g < end) ? w : 0.f;
            float x0 = __uint_as_float(vv[p].x << 16);
            float x1 = __uint_as_float(vv[p].x & 0xffff0000u);
            float x2 = __uint_as_float(vv[p].y << 16);
            float x3 = __uint_as_float(vv[p].y & 0xffff0000u);
            acc.x += w * x0; acc.y += w * x1;
            acc.z += w * x2; acc.w += w * x3;
            dsum += w;
        }
#pragma unroll
        for (int p = 0; p < 4; ++p) sA[p] = sB[p];
    }

#pragma unroll
    for (int ofs = 8; ofs <= 32; ofs <<= 1) {
        acc.x += __shfl_xor(acc.x, ofs);
        acc.y += __shfl_xor(acc.y, ofs);
        acc.z += __shfl_xor(acc.z, ofs);
        acc.w += __shfl_xor(acc.w, ofs);
        dsum  += __shfl_xor(dsum, ofs);
    }

    if (g == 0) {
        float inv = 1.f / (dsum + 1e-16f);
        const float4 bq = reinterpret_cast<const float4*>(bias2)[q];
        float4 r;
        r.x = acc.x * inv + bq.x;
        r.y = acc.y * inv + bq.y;
        r.z = acc.z * inv + bq.z;
        r.w = acc.w * inv + bq.w;
        reinterpret_cast<float4*>(o2)[dst * 8 + q] = r;
    }
}

// ---------------- K9: pooled sums.
__global__ __launch_bounds__(256) void k_pool(const float* __restrict__ o2, const int* __restrict__ lo,
                                              float* __restrict__ pooled) {
    __shared__ float red[256];
    int g = blockIdx.x & 63, q = blockIdx.x >> 6;
    int beg = lo[g], end = lo[g + 1];
    int c = threadIdx.x & 31, row = threadIdx.x >> 5;
    float s = 0.f;
    for (int n = beg + q * 8 + row; n < end; n += 32) s += o2[n * 32 + c];
    red[threadIdx.x] = s;
    __syncthreads();
    for (int rr = 4; rr >= 1; rr >>= 1) {
        if (row < rr) red[threadIdx.x] += red[(row + rr) * 32 + c];
        __syncthreads();
    }
    if (row == 0) atomicAdd(&pooled[g * 32 + c], red[c]);
}

// ---------------- K10: mean + final linear -> out[64][2]
__global__ void k_fin(const float* __restrict__ pooled, const int* __restrict__ lo,
                      const float* __restrict__ lw, const float* __restrict__ lb,
                      float* __restrict__ out) {
    int t = threadIdx.x;
    if (t >= 128) return;
    int g = t >> 1, o = t & 1;
    int cnt = lo[g + 1] - lo[g];
    float inv = 1.f / fmaxf((float)cnt, 1.f);
    float s = 0.f;
#pragma unroll
    for (int c = 0; c < 32; ++c) s += pooled[g * 32 + c] * lw[c * 2 + o];
    out[g * 2 + o] = s * inv + lb[o];
}

// ----------------------------------------------------------------------------
extern "C" void kernel_launch(void* const* d_in, const int* in_sizes, int n_in,
                              void* d_out, int out_size, void* d_ws, size_t ws_size,
                              hipStream_t stream) {
    const float* x   = (const float*)d_in[0];
    const int*   ei  = (const int*)d_in[1];     // [2][NE]
    const int*   bat = (const int*)d_in[2];
    const float* W1  = (const float*)d_in[3];
    const float* aS1 = (const float*)d_in[4];
    const float* aD1 = (const float*)d_in[5];
    const float* b1  = (const float*)d_in[6];
    const float* W2  = (const float*)d_in[7];
    const float* aS2 = (const float*)d_in[8];
    const float* aD2 = (const float*)d_in[9];
    const float* b2  = (const float*)d_in[10];
    const float* lw  = (const float*)d_in[11];
    const float* lb  = (const float*)d_in[12];
    float* out = (float*)d_out;

    const int* esrc = ei;
    const int* edst = ei + NE;

    char* ws = (char*)d_ws;
    size_t off = 0;
    auto alloc = [&](size_t bytes) -> void* {
        off = (off + 255) & ~(size_t)255;
        void* p = ws + off;
        off += bytes;
        return p;
    };

    unsigned short* h1b = (unsigned short*)alloc((size_t)NN * 64 * 2);
    unsigned short* h2b = (unsigned short*)alloc((size_t)NN * 32 * 2);
    float* o2   = (float*)alloc((size_t)NN * 32 * 4);
    float* as1  = (float*)alloc((size_t)NN * 8 * 4);
    float* ad1  = (float*)alloc((size_t)NN * 8 * 4);
    float* as2  = (float*)alloc((size_t)NN * 4);
    float* ad2  = (float*)alloc((size_t)NN * 4);
    int*   obeg = (int*)alloc((size_t)NN * 4);
    int*   oend = (int*)alloc((size_t)NN * 4);
    int*   csr  = (int*)alloc((size_t)NB * CAP * 4);
    unsigned* rec = (unsigned*)alloc((size_t)NB * CAP * 4);
    int*   gcnt = (int*)alloc((size_t)NB * 4);
    unsigned short* w1f = (unsigned short*)alloc((size_t)512 * 64 * 2);
    float* pooled = (float*)alloc((size_t)NG * 32 * 4);
    int*   lo   = (int*)alloc((size_t)(NG + 1) * 4);
    if (off > ws_size) return;   // workspace too small: leave d_out poisoned (visible failure)

    hipMemsetAsync(gcnt, 0, (size_t)NB * 4, stream);
    hipMemsetAsync(pooled, 0, (size_t)NG * 32 * 4, stream);

    k_wf<<<16, 256, 0, stream>>>(W1, w1f);
    k_fa<<<G1H + BIN_BLOCKS + SCAN_BLOCKS, 256, 0, stream>>>(
        x, w1f, aS1, aD1, h1b, as1, ad1, esrc, edst, gcnt, rec, bat, lo);
    k_fb<<<G1H + NB, 256, 0, stream>>>(
        x, w1f, aS1, aD1, h1b, as1, ad1, gcnt, rec, obeg, oend, csr);

    k_agg1g<<<(NN + 3) / 4, 256, 0, stream>>>(obeg, oend, csr, h1b, as1, ad1, b1,
                                              W2, aS2, aD2, h2b, as2, ad2);
    k_agg2<<<(NN + 3) / 4, 256, 0, stream>>>(obeg, oend, csr, h2b, as2, ad2, b2, o2);

    k_pool<<<NG * 4, 256, 0, stream>>>(o2, lo, pooled);
    k_fin<<<1, 128, 0, stream>>>(pooled, lo, lw, lb, out);
}

// Round 28
// 142.019 us; speedup vs baseline: 1.1140x; 1.0479x over previous
//
#include <hip/hip_runtime.h>
#include <cstdint>
#include <cstddef>

#define NN 50000
#define NE 1600000
#define ET (NE + NN)          // edges + self loops
#define NG 64
#define SCAN_BLOCKS ((NN + 255) / 256)   // 196
#define NB ((NN + 127) >> 7)             // 391 dst-buckets, 128 nodes each
#define CAP 6144                         // slots per bucket segment
#define EPT 16
#define EPB (256 * EPT)                  // 4096 edges per bin-block
#define BIN_BLOCKS ((ET + EPB - 1) / EPB)
#define G1H 391                          // gemm1 half-grid (782 total)

typedef __attribute__((ext_vector_type(8))) short short8v;
typedef __attribute__((ext_vector_type(4))) float f32x4;

__device__ inline unsigned short f2bf(float f) {
    unsigned u = __float_as_uint(f);
    u += 0x7fffu + ((u >> 16) & 1u);     // round-to-nearest-even
    return (unsigned short)(u >> 16);
}

// ---- gemm1 block body: 64 rows at n0, MFMA bf16, direct fp32 A loads.
__device__ __forceinline__ void gemm1_block(
    int n0, int t,
    const float* __restrict__ x, const unsigned short* __restrict__ w1f,
    const float* __restrict__ aS, const float* __restrict__ aD,
    unsigned short* __restrict__ h1b, float* __restrict__ as1, float* __restrict__ ad1) {
    int w = t >> 6, l = t & 63;
    int rrow = n0 + w * 16 + (l & 15);
    int rc = (rrow < NN) ? rrow : (NN - 1);
    const float* __restrict__ xr = x + (size_t)rc * 512;
    const short8v* __restrict__ wv8 = reinterpret_cast<const short8v*>(w1f);

    f32x4 acc0 = {0.f, 0.f, 0.f, 0.f};
    f32x4 acc1 = {0.f, 0.f, 0.f, 0.f};
    f32x4 acc2 = {0.f, 0.f, 0.f, 0.f};
    f32x4 acc3 = {0.f, 0.f, 0.f, 0.f};

    int lk = (l >> 4) << 3;   // k-offset of this lane's A frag within a 32-k step
#pragma unroll 4
    for (int s = 0; s < 16; ++s) {
        const float4* xp = reinterpret_cast<const float4*>(xr + s * 32 + lk);
        float4 a0 = xp[0];
        float4 a1 = xp[1];
        short8v af;
        af[0] = (short)f2bf(a0.x); af[1] = (short)f2bf(a0.y);
        af[2] = (short)f2bf(a0.z); af[3] = (short)f2bf(a0.w);
        af[4] = (short)f2bf(a1.x); af[5] = (short)f2bf(a1.y);
        af[6] = (short)f2bf(a1.z); af[7] = (short)f2bf(a1.w);
        const short8v* bp = wv8 + (size_t)(s * 4) * 64 + l;
        short8v bf0 = bp[0];
        short8v bf1 = bp[64];
        short8v bf2 = bp[128];
        short8v bf3 = bp[192];
        acc0 = __builtin_amdgcn_mfma_f32_16x16x32_bf16(af, bf0, acc0, 0, 0, 0);
        acc1 = __builtin_amdgcn_mfma_f32_16x16x32_bf16(af, bf1, acc1, 0, 0, 0);
        acc2 = __builtin_amdgcn_mfma_f32_16x16x32_bf16(af, bf2, acc2, 0, 0, 0);
        acc3 = __builtin_amdgcn_mfma_f32_16x16x32_bf16(af, bf3, acc3, 0, 0, 0);
    }

    // epilogue: C/D layout col=lane&15, row=(lane>>4)*4+reg (m89-verified)
    int hi = (l & 15) >> 3;
    int cc = l & 7;
#pragma unroll
    for (int reg = 0; reg < 4; ++reg) {
        int row16 = ((l >> 4) << 2) + reg;
        int r = n0 + w * 16 + row16;
        float v0 = acc0[reg], v1 = acc1[reg], v2 = acc2[reg], v3 = acc3[reg];
        if (r < NN) {
            unsigned short* hp = h1b + (size_t)r * 64 + (l & 15);
            hp[0]  = f2bf(v0);
            hp[16] = f2bf(v1);
            hp[32] = f2bf(v2);
            hp[48] = f2bf(v3);
        }
        float ps[4], pd[4];
        float vv[4] = {v0, v1, v2, v3};
#pragma unroll
        for (int ct = 0; ct < 4; ++ct) {
            int h = ct * 2 + hi;
            ps[ct] = vv[ct] * aS[h * 8 + cc];
            pd[ct] = vv[ct] * aD[h * 8 + cc];
        }
#pragma unroll
        for (int ofs = 1; ofs <= 4; ofs <<= 1) {
#pragma unroll
            for (int ct = 0; ct < 4; ++ct) {
                ps[ct] += __shfl_xor(ps[ct], ofs);
                pd[ct] += __shfl_xor(pd[ct], ofs);
            }
        }
        if (cc == 0 && r < NN) {
#pragma unroll
            for (int ct = 0; ct < 4; ++ct) {
                int h = ct * 2 + hi;
                as1[r * 8 + h] = ps[ct];
                ad1[r * 8 + h] = pd[ct];
            }
        }
    }
}

// ---------------- WF: wfrag (blocks 0..15) + zero gcnt (block 16) + zero pooled (block 17).
__global__ __launch_bounds__(256) void k_wf(const float* __restrict__ W1,
                                            unsigned short* __restrict__ w1f,
                                            int* __restrict__ gcnt,
                                            float* __restrict__ pooled) {
    int bid = blockIdx.x, tid = threadIdx.x;
    if (bid < 16) {
        int slot = bid * 256 + tid;   // 0..4095
        int S = slot >> 8;
        int ct = (slot >> 6) & 3;
        int l = slot & 63;
        int kb = S * 32 + ((l >> 4) << 3);
        int c = ct * 16 + (l & 15);
        unsigned short* dst = w1f + (size_t)slot * 8;
#pragma unroll
        for (int j = 0; j < 8; ++j)
            dst[j] = f2bf(W1[(kb + j) * 64 + c]);
    } else if (bid == 16) {
        for (int b = tid; b < NB; b += 256) gcnt[b] = 0;
    } else {
        for (int i = tid; i < NG * 32; i += 256) pooled[i] = 0.f;
    }
}

// ---------------- FA: gemm1-half1 (391) || bin (403) || bound (196)
__global__ __launch_bounds__(256) void k_fa(
    const float* __restrict__ x, const unsigned short* __restrict__ w1f,
    const float* __restrict__ aS, const float* __restrict__ aD,
    unsigned short* __restrict__ h1b, float* __restrict__ as1, float* __restrict__ ad1,
    const int* __restrict__ esrc, const int* __restrict__ edst,
    int* __restrict__ gcnt, unsigned* __restrict__ rec,
    const int* __restrict__ batch, int* __restrict__ lo) {
    __shared__ int bcnt[NB];
    int bid = blockIdx.x, tid = threadIdx.x;
    if (bid < G1H) {
        gemm1_block(bid * 64, tid, x, w1f, aS, aD, h1b, as1, ad1);
    } else if (bid < G1H + BIN_BLOCKS) {
        // ---- bin: block-aggregated bucket scatter into fixed segments
        for (int b = tid; b < NB; b += 256) bcnt[b] = 0;
        __syncthreads();
        int e0 = (bid - G1H) * EPB;
        unsigned rv[EPT]; int bk[EPT]; int rk[EPT];
#pragma unroll
        for (int q = 0; q < EPT; ++q) {
            int e = e0 + q * 256 + tid;
            rk[q] = -1;
            if (e < ET) {
                int s, d;
                if (e < NE) { s = esrc[e]; d = edst[e]; } else { s = d = e - NE; }
                rv[q] = ((unsigned)s << 7) | (unsigned)(d & 127);
                bk[q] = d >> 7;
                rk[q] = atomicAdd(&bcnt[bk[q]], 1);
            }
        }
        __syncthreads();
        for (int b = tid; b < NB; b += 256)
            bcnt[b] = atomicAdd(&gcnt[b], bcnt[b]);
        __syncthreads();
#pragma unroll
        for (int q = 0; q < EPT; ++q) {
            if (rk[q] >= 0) rec[(size_t)bk[q] * CAP + bcnt[bk[q]] + rk[q]] = rv[q];
        }
    } else {
        // ---- bound
        int n = (bid - G1H - BIN_BLOCKS) * 256 + tid;
        if (n >= NN) return;
        int b = batch[n];
        if (n == 0) {
            for (int g = 0; g <= b; ++g) lo[g] = 0;
        } else {
            int pb = batch[n - 1];
            for (int g = pb + 1; g <= b; ++g) lo[g] = n;
        }
        if (n == NN - 1) {
            for (int g = b + 1; g <= NG; ++g) lo[g] = NN;
        }
    }
}

// ---------------- FB: gemm1-half2 (391) || unbin2 (391)
__global__ __launch_bounds__(256) void k_fb(
    const float* __restrict__ x, const unsigned short* __restrict__ w1f,
    const float* __restrict__ aS, const float* __restrict__ aD,
    unsigned short* __restrict__ h1b, float* __restrict__ as1, float* __restrict__ ad1,
    const int* __restrict__ gcnt, const unsigned* __restrict__ rec,
    int* __restrict__ obeg, int* __restrict__ oend, int* __restrict__ csr) {
    __shared__ int sm[256];
    int bid = blockIdx.x, tid = threadIdx.x;
    if (bid < G1H) {
        gemm1_block((G1H + bid) * 64, tid, x, w1f, aS, aD, h1b, as1, ad1);
    } else {
        // ======== unbin2 ========
        int* cnt  = sm;
        int* lcur = sm + 128;
        int b = bid - G1H;
        if (tid < 128) cnt[tid] = 0;
        __syncthreads();
        size_t base = (size_t)b * CAP;
        int nrec = gcnt[b];
        for (int i = tid; i < nrec; i += 256)
            atomicAdd(&cnt[rec[base + i] & 127], 1);
        __syncthreads();
        int v = 0, incl = 0;
        if (tid < 128) {
            int lane = tid & 63;
            v = cnt[tid];
            incl = v;
#pragma unroll
            for (int ofs = 1; ofs < 64; ofs <<= 1) {
                int o = __shfl_up(incl, ofs);
                if (lane >= ofs) incl += o;
            }
            cnt[tid] = incl;
        }
        __syncthreads();
        if (tid < 128) {
            int ex = incl - v + ((tid >= 64) ? cnt[63] : 0);
            int n = (b << 7) + tid;
            int pos = (int)base + ex;
            if (n < NN) { obeg[n] = pos; oend[n] = pos + v; }
            lcur[tid] = pos;
        }
        __syncthreads();
        for (int i = tid; i < nrec; i += 256) {
            unsigned r = rec[base + i];
            int pos = atomicAdd(&lcur[r & 127], 1);
            csr[pos] = (int)(r >> 7);
        }
    }
}

// ---------------- K4: fused layer-1 aggregation + layer-2 GEMM. h1 gathered as bf16.
__global__ __launch_bounds__(256) void k_agg1g(
    const int* __restrict__ obeg, const int* __restrict__ oend, const int* __restrict__ csr,
    const unsigned short* __restrict__ h1b, const float* __restrict__ as1, const float* __restrict__ ad1,
    const float* __restrict__ bias1, const float* __restrict__ W2,
    const float* __restrict__ aS2, const float* __restrict__ aD2,
    unsigned short* __restrict__ h2b, float* __restrict__ as2, float* __restrict__ ad2) {
    __shared__ float w2l[64 * 32];     // 8 KB
    __shared__ float h1ol[4][64];      // per-wave h1o row
    int tid = threadIdx.x;
    for (int i = tid; i < 2048; i += 256) w2l[i] = W2[i];
    __syncthreads();

    int l = tid & 63;
    int wv = tid >> 6;
    int dst = blockIdx.x * 4 + wv;
    if (dst >= NN) return;
    int g = l >> 4;            // edge slot 0..3
    int q = l & 15;            // 4-channel group
    int h = q >> 1;            // head
    int beg = obeg[dst], end = oend[dst];
    int lastj = end - 1;
    float adh = ad1[dst * 8 + h];
    const uint2* __restrict__ h1u = reinterpret_cast<const uint2*>(h1b);

    float4 acc = make_float4(0.f, 0.f, 0.f, 0.f);
    float dsum = 0.f;

    int sA[4], sB[4];
#pragma unroll
    for (int p = 0; p < 4; ++p) sA[p] = csr[min(beg + p * 4 + g, lastj)];
    for (int j = beg; j < end; j += 16) {
#pragma unroll
        for (int p = 0; p < 4; ++p) sB[p] = csr[min(j + 16 + p * 4 + g, lastj)];
        float av[4]; uint2 vv[4];
#pragma unroll
        for (int p = 0; p < 4; ++p) {
            av[p] = as1[sA[p] * 8 + h];
            vv[p] = h1u[(size_t)sA[p] * 16 + q];
        }
#pragma unroll
        for (int p = 0; p < 4; ++p) {
            float e = av[p] + adh; e = (e > 0.f) ? e : 0.2f * e;
            float w = __expf(e);
            w = (j + p * 4 + g < end) ? w : 0.f;
            float x0 = __uint_as_float(vv[p].x << 16);
            float x1 = __uint_as_float(vv[p].x & 0xffff0000u);
            float x2 = __uint_as_float(vv[p].y << 16);
            float x3 = __uint_as_float(vv[p].y & 0xffff0000u);
            acc.x += w * x0; acc.y += w * x1;
            acc.z += w * x2; acc.w += w * x3;
            dsum += w;
        }
#pragma unroll
        for (int p = 0; p < 4; ++p) sA[p] = sB[p];
    }

#pragma unroll
    for (int ofs = 16; ofs <= 32; ofs <<= 1) {
        acc.x += __shfl_xor(acc.x, ofs);
        acc.y += __shfl_xor(acc.y, ofs);
        acc.z += __shfl_xor(acc.z, ofs);
        acc.w += __shfl_xor(acc.w, ofs);
        dsum  += __shfl_xor(dsum, ofs);
    }

    if (g == 0) {
        float inv = 1.f / (dsum + 1e-16f);
        const float4 bq = reinterpret_cast<const float4*>(bias1)[q];
        float4 r;
        r.x = acc.x * inv + bq.x;
        r.y = acc.y * inv + bq.y;
        r.z = acc.z * inv + bq.z;
        r.w = acc.w * inv + bq.w;
        r.x = (r.x > 0.f) ? r.x : (__expf(r.x) - 1.f);
        r.y = (r.y > 0.f) ? r.y : (__expf(r.y) - 1.f);
        r.z = (r.z > 0.f) ? r.z : (__expf(r.z) - 1.f);
        r.w = (r.w > 0.f) ? r.w : (__expf(r.w) - 1.f);
        h1ol[wv][q * 4 + 0] = r.x;
        h1ol[wv][q * 4 + 1] = r.y;
        h1ol[wv][q * 4 + 2] = r.z;
        h1ol[wv][q * 4 + 3] = r.w;
    }

    // fused gemm2; h2 stored bf16
    int c = l & 31, half = l >> 5;
    const float* hrow = h1ol[wv];
    float acc2 = 0.f;
#pragma unroll 8
    for (int kk = 0; kk < 32; ++kk) {
        int k = half * 32 + kk;
        acc2 += hrow[k] * w2l[k * 32 + c];
    }
    acc2 += __shfl_xor(acc2, 32);
    if (l < 32) h2b[(size_t)dst * 32 + c] = f2bf(acc2);
    float ps = acc2 * aS2[c], pd = acc2 * aD2[c];
#pragma unroll
    for (int ofs = 1; ofs <= 16; ofs <<= 1) {
        ps += __shfl_xor(ps, ofs);
        pd += __shfl_xor(pd, ofs);
    }
    if (l == 0) { as2[dst] = ps; ad2[dst] = pd; }
}

// ---------------- K7: layer-2 aggregation; h2 gathered as bf16. o2 fp32.
__global__ __launch_bounds__(256) void k_agg2(
    const int* __restrict__ obeg, const int* __restrict__ oend, const int* __restrict__ csr,
    const unsigned short* __restrict__ h2b, const float* __restrict__ as2, const float* __restrict__ ad2,
    const float* __restrict__ bias2, float* __restrict__ o2) {
    int l = threadIdx.x & 63;
    int dst = blockIdx.x * 4 + (threadIdx.x >> 6);
    if (dst >= NN) return;
    int g = l >> 3;            // edge slot 0..7
    int q = l & 7;             // 4-channel group
    int beg = obeg[dst], end = oend[dst];
    int lastj = end - 1;
    float adh = ad2[dst];
    const uint2* __restrict__ h2u = reinterpret_cast<const uint2*>(h2b);

    float4 acc = make_float4(0.f, 0.f, 0.f, 0.f);
    float dsum = 0.f;

    int sA[4], sB[4];
#pragma unroll
    for (int p = 0; p < 4; ++p) sA[p] = csr[min(beg + p * 8 + g, lastj)];
    for (int j = beg; j < end; j += 32) {
#pragma unroll
        for (int p = 0; p < 4; ++p) sB[p] = csr[min(j + 32 + p * 8 + g, lastj)];
        float av[4]; uint2 vv[4];
#pragma unroll
        for (int p = 0; p < 4; ++p) {
            av[p] = as2[sA[p]];
            vv[p] = h2u[(size_t)sA[p] * 8 + q];
        }
#pragma unroll
        for (int p = 0; p < 4; ++p) {
            float e = av[p] + adh; e = (e > 0.f) ? e : 0.2f * e;
            float w = __expf(e);
            w = (j + p * 8 + g < end) ? w : 0.f;
            float x0 = __uint_as_float(vv[p].x << 16);
            float x1 = __uint_as_float(vv[p].x & 0xffff0000u);
            float x2 = __uint_as_float(vv[p].y << 16);
            float x3 = __uint_as_float(vv[p].y & 0xffff0000u);
            acc.x += w * x0; acc.y += w * x1;
            acc.z += w * x2; acc.w += w * x3;
            dsum += w;
        }
#pragma unroll
        for (int p = 0; p < 4; ++p) sA[p] = sB[p];
    }

#pragma unroll
    for (int ofs = 8; ofs <= 32; ofs <<= 1) {
        acc.x += __shfl_xor(acc.x, ofs);
        acc.y += __shfl_xor(acc.y, ofs);
        acc.z += __shfl_xor(acc.z, ofs);
        acc.w += __shfl_xor(acc.w, ofs);
        dsum  += __shfl_xor(dsum, ofs);
    }

    if (g == 0) {
        float inv = 1.f / (dsum + 1e-16f);
        const float4 bq = reinterpret_cast<const float4*>(bias2)[q];
        float4 r;
        r.x = acc.x * inv + bq.x;
        r.y = acc.y * inv + bq.y;
        r.z = acc.z * inv + bq.z;
        r.w = acc.w * inv + bq.w;
        reinterpret_cast<float4*>(o2)[dst * 8 + q] = r;
    }
}

// ---------------- K9: pooled sums.
__global__ __launch_bounds__(256) void k_pool(const float* __restrict__ o2, const int* __restrict__ lo,
                                              float* __restrict__ pooled) {
    __shared__ float red[256];
    int g = blockIdx.x & 63, q = blockIdx.x >> 6;
    int beg = lo[g], end = lo[g + 1];
    int c = threadIdx.x & 31, row = threadIdx.x >> 5;
    float s = 0.f;
    for (int n = beg + q * 8 + row; n < end; n += 32) s += o2[n * 32 + c];
    red[threadIdx.x] = s;
    __syncthreads();
    for (int rr = 4; rr >= 1; rr >>= 1) {
        if (row < rr) red[threadIdx.x] += red[(row + rr) * 32 + c];
        __syncthreads();
    }
    if (row == 0) atomicAdd(&pooled[g * 32 + c], red[c]);
}

// ---------------- K10: mean + final linear -> out[64][2]
__global__ void k_fin(const float* __restrict__ pooled, const int* __restrict__ lo,
                      const float* __restrict__ lw, const float* __restrict__ lb,
                      float* __restrict__ out) {
    int t = threadIdx.x;
    if (t >= 128) return;
    int g = t >> 1, o = t & 1;
    int cnt = lo[g + 1] - lo[g];
    float inv = 1.f / fmaxf((float)cnt, 1.f);
    float s = 0.f;
#pragma unroll
    for (int c = 0; c < 32; ++c) s += pooled[g * 32 + c] * lw[c * 2 + o];
    out[g * 2 + o] = s * inv + lb[o];
}

// ----------------------------------------------------------------------------
extern "C" void kernel_launch(void* const* d_in, const int* in_sizes, int n_in,
                              void* d_out, int out_size, void* d_ws, size_t ws_size,
                              hipStream_t stream) {
    const float* x   = (const float*)d_in[0];
    const int*   ei  = (const int*)d_in[1];     // [2][NE]
    const int*   bat = (const int*)d_in[2];
    const float* W1  = (const float*)d_in[3];
    const float* aS1 = (const float*)d_in[4];
    const float* aD1 = (const float*)d_in[5];
    const float* b1  = (const float*)d_in[6];
    const float* W2  = (const float*)d_in[7];
    const float* aS2 = (const float*)d_in[8];
    const float* aD2 = (const float*)d_in[9];
    const float* b2  = (const float*)d_in[10];
    const float* lw  = (const float*)d_in[11];
    const float* lb  = (const float*)d_in[12];
    float* out = (float*)d_out;

    const int* esrc = ei;
    const int* edst = ei + NE;

    char* ws = (char*)d_ws;
    size_t off = 0;
    auto alloc = [&](size_t bytes) -> void* {
        off = (off + 255) & ~(size_t)255;
        void* p = ws + off;
        off += bytes;
        return p;
    };

    unsigned short* h1b = (unsigned short*)alloc((size_t)NN * 64 * 2);
    unsigned short* h2b = (unsigned short*)alloc((size_t)NN * 32 * 2);
    float* o2   = (float*)alloc((size_t)NN * 32 * 4);
    float* as1  = (float*)alloc((size_t)NN * 8 * 4);
    float* ad1  = (float*)alloc((size_t)NN * 8 * 4);
    float* as2  = (float*)alloc((size_t)NN * 4);
    float* ad2  = (float*)alloc((size_t)NN * 4);
    int*   obeg = (int*)alloc((size_t)NN * 4);
    int*   oend = (int*)alloc((size_t)NN * 4);
    int*   csr  = (int*)alloc((size_t)NB * CAP * 4);
    unsigned* rec = (unsigned*)alloc((size_t)NB * CAP * 4);
    int*   gcnt = (int*)alloc((size_t)NB * 4);
    unsigned short* w1f = (unsigned short*)alloc((size_t)512 * 64 * 2);
    float* pooled = (float*)alloc((size_t)NG * 32 * 4);
    int*   lo   = (int*)alloc((size_t)(NG + 1) * 4);
    if (off > ws_size) return;   // workspace too small: leave d_out poisoned (visible failure)

    k_wf<<<18, 256, 0, stream>>>(W1, w1f, gcnt, pooled);
    k_fa<<<G1H + BIN_BLOCKS + SCAN_BLOCKS, 256, 0, stream>>>(
        x, w1f, aS1, aD1, h1b, as1, ad1, esrc, edst, gcnt, rec, bat, lo);
    k_fb<<<G1H + NB, 256, 0, stream>>>(
        x, w1f, aS1, aD1, h1b, as1, ad1, gcnt, rec, obeg, oend, csr);

    k_agg1g<<<(NN + 3) / 4, 256, 0, stream>>>(obeg, oend, csr, h1b, as1, ad1, b1,
                                              W2, aS2, aD2, h2b, as2, ad2);
    k_agg2<<<(NN + 3) / 4, 256, 0, stream>>>(obeg, oend, csr, h2b, as2, ad2, b2, o2);

    k_pool<<<NG * 4, 256, 0, stream>>>(o2, lo, pooled);
    k_fin<<<1, 128, 0, stream>>>(pooled, lo, lw, lb, out);
}